// Round 1
// baseline (24.093 us; speedup 1.0000x reference)
//
#include <hip/hip_runtime.h>

#define BATCH 4
#define N_CH 3
#define NUM_CLASSES 20
#define IMG_H 512
#define IMG_W 512
#define MAX_BOXES 50
#define SPLIT 8          // blocks per box (load-balance large boxes)
#define BLOCK 256

// One (box, part) per block. Accumulate sum over box region of
// sum_n (im_data[b,n,y,x] - y_fcn[b, cls*N_CH+n, y, x])^2,
// then atomicAdd( sum / (N_CH * area) ) into acc[0].
__global__ void box_err_kernel(const float* __restrict__ y_fcn,
                               const float* __restrict__ im_data,
                               const int*   __restrict__ gt_boxes,
                               const int*   __restrict__ num_boxes,
                               float*       __restrict__ acc) {
    const int slot = blockIdx.x / SPLIT;          // 0 .. BATCH*MAX_BOXES-1
    const int part = blockIdx.x % SPLIT;
    const int b    = slot / MAX_BOXES;
    const int box  = slot % MAX_BOXES;

    if (box >= num_boxes[b]) return;              // invalid slot -> contributes 0

    const int* g  = gt_boxes + (slot * 5);
    const int x1 = g[0], y1 = g[1], x2 = g[2], y2 = g[3], cls = g[4];
    const int bw = x2 - x1;
    const int bh = y2 - y1;
    const int area = bw * bh;
    const int total = area;                       // pixels in box

    const size_t plane = (size_t)IMG_H * IMG_W;
    const float* im = im_data + (size_t)b * N_CH * plane;
    const float* yf = y_fcn + ((size_t)b * NUM_CLASSES + cls) * N_CH * plane;

    float s = 0.0f;
    const int tid    = part * BLOCK + (int)threadIdx.x;
    const int stride = SPLIT * BLOCK;
    for (int p = tid; p < total; p += stride) {
        const int ry = p / bw;
        const int rx = p - ry * bw;
        const int off = (y1 + ry) * IMG_W + (x1 + rx);
        #pragma unroll
        for (int nn = 0; nn < N_CH; ++nn) {
            const float d = im[nn * plane + off] - yf[nn * plane + off];
            s = fmaf(d, d, s);
        }
    }

    // wave (64-lane) shuffle reduction
    #pragma unroll
    for (int off = 32; off > 0; off >>= 1)
        s += __shfl_down(s, off, 64);

    // cross-wave reduction via LDS
    __shared__ float red[BLOCK / 64];
    const int lane = threadIdx.x & 63;
    const int wave = threadIdx.x >> 6;
    if (lane == 0) red[wave] = s;
    __syncthreads();
    if (threadIdx.x == 0) {
        float t = 0.0f;
        #pragma unroll
        for (int w = 0; w < BLOCK / 64; ++w) t += red[w];
        const float denom = (float)(N_CH * max(area, 1));
        atomicAdd(acc, t / denom);
    }
}

__global__ void finalize_kernel(const float* __restrict__ acc,
                                const int*   __restrict__ num_boxes,
                                float*       __restrict__ out) {
    if (threadIdx.x == 0 && blockIdx.x == 0) {
        int tot = 0;
        #pragma unroll
        for (int b = 0; b < BATCH; ++b) tot += num_boxes[b];
        out[0] = acc[0] / (float)tot;
    }
}

extern "C" void kernel_launch(void* const* d_in, const int* in_sizes, int n_in,
                              void* d_out, int out_size, void* d_ws, size_t ws_size,
                              hipStream_t stream) {
    const float* y_fcn    = (const float*)d_in[0];
    const float* im_data  = (const float*)d_in[1];
    // d_in[2] = im_info (unused)
    const int*   gt_boxes = (const int*)d_in[3];
    const int*   num_boxes= (const int*)d_in[4];
    float* out = (float*)d_out;
    float* acc = (float*)d_ws;

    // zero the accumulator each call (ws is poisoned once, never re-poisoned)
    hipMemsetAsync(acc, 0, sizeof(float), stream);

    box_err_kernel<<<BATCH * MAX_BOXES * SPLIT, BLOCK, 0, stream>>>(
        y_fcn, im_data, gt_boxes, num_boxes, acc);

    finalize_kernel<<<1, 64, 0, stream>>>(acc, num_boxes, out);
}

// Round 2
// 23.540 us; speedup vs baseline: 1.0235x; 1.0235x over previous
//
#include <hip/hip_runtime.h>

#define BATCH 4
#define N_CH 3
#define NUM_CLASSES 20
#define IMG_H 512
#define IMG_W 512
#define MAX_BOXES 50
#define SPLIT 8          // blocks per box (load-balance large boxes)
#define BLOCK 256

// One (box, part) per block. Accumulate sum over box region of
// sum_n (im_data[b,n,y,x] - y_fcn[b, cls*N_CH+n, y, x])^2,
// then atomicAdd( sum / (N_CH * area * tot_boxes) ) directly into out[0].
// out[0] is zeroed by a 4-byte memset node preceding this kernel.
__global__ void box_err_kernel(const float* __restrict__ y_fcn,
                               const float* __restrict__ im_data,
                               const int*   __restrict__ gt_boxes,
                               const int*   __restrict__ num_boxes,
                               float*       __restrict__ out) {
    const int slot = blockIdx.x / SPLIT;          // 0 .. BATCH*MAX_BOXES-1
    const int part = blockIdx.x % SPLIT;
    const int b    = slot / MAX_BOXES;
    const int box  = slot % MAX_BOXES;

    if (box >= num_boxes[b]) return;              // invalid slot -> contributes 0

    const int* g  = gt_boxes + (slot * 5);
    const int x1 = g[0], y1 = g[1], x2 = g[2], y2 = g[3], cls = g[4];
    const int bw = x2 - x1;
    const int bh = y2 - y1;
    const int area = bw * bh;

    const size_t plane = (size_t)IMG_H * IMG_W;
    const float* im = im_data + (size_t)b * N_CH * plane;
    const float* yf = y_fcn + ((size_t)b * NUM_CLASSES + cls) * N_CH * plane;

    // rows round-robin over parts; lanes stride across the row (coalesced,
    // no integer div in the inner loop)
    float s = 0.0f;
    for (int ry = part; ry < bh; ry += SPLIT) {
        const int row = (y1 + ry) * IMG_W + x1;
        for (int rx = (int)threadIdx.x; rx < bw; rx += BLOCK) {
            const int off = row + rx;
            #pragma unroll
            for (int nn = 0; nn < N_CH; ++nn) {
                const float d = im[nn * plane + off] - yf[nn * plane + off];
                s = fmaf(d, d, s);
            }
        }
    }

    // wave (64-lane) shuffle reduction
    #pragma unroll
    for (int off = 32; off > 0; off >>= 1)
        s += __shfl_down(s, off, 64);

    // cross-wave reduction via LDS
    __shared__ float red[BLOCK / 64];
    const int lane = threadIdx.x & 63;
    const int wave = threadIdx.x >> 6;
    if (lane == 0) red[wave] = s;
    __syncthreads();
    if (threadIdx.x == 0) {
        float t = 0.0f;
        #pragma unroll
        for (int w = 0; w < BLOCK / 64; ++w) t += red[w];
        int tot = 0;
        #pragma unroll
        for (int bb = 0; bb < BATCH; ++bb) tot += num_boxes[bb];
        const float denom = (float)(N_CH * max(area, 1)) * (float)tot;
        atomicAdd(out, t / denom);
    }
}

extern "C" void kernel_launch(void* const* d_in, const int* in_sizes, int n_in,
                              void* d_out, int out_size, void* d_ws, size_t ws_size,
                              hipStream_t stream) {
    const float* y_fcn    = (const float*)d_in[0];
    const float* im_data  = (const float*)d_in[1];
    // d_in[2] = im_info (unused)
    const int*   gt_boxes = (const int*)d_in[3];
    const int*   num_boxes= (const int*)d_in[4];
    float* out = (float*)d_out;

    // zero the output each call (replays must not accumulate)
    hipMemsetAsync(out, 0, sizeof(float), stream);

    box_err_kernel<<<BATCH * MAX_BOXES * SPLIT, BLOCK, 0, stream>>>(
        y_fcn, im_data, gt_boxes, num_boxes, out);
}